// Round 2
// baseline (699.334 us; speedup 1.0000x reference)
//
#include <hip/hip_runtime.h>
#include <stdint.h>

#define H_DIM 256
#define NCOL 8192
#define TOPK 512
#define CAND_CAP 8192

typedef unsigned short u16;
typedef __attribute__((ext_vector_type(8))) __bf16 bf16x8;
typedef __attribute__((ext_vector_type(4))) float f32x4;
typedef unsigned __attribute__((address_space(3))) lds_u32;
typedef const unsigned __attribute__((address_space(1))) glb_u32;

// monotonic float -> uint key (order-preserving for all finite floats)
__device__ __forceinline__ unsigned fkey(float f) {
  unsigned u = __float_as_uint(f);
  unsigned m = (unsigned)((int)u >> 31) | 0x80000000u;
  return u ^ m;
}

__device__ __forceinline__ u16 f2bf_rne(float f) {
  unsigned u = __float_as_uint(f);
  return (u16)((u + 0x7fffu + ((u >> 16) & 1u)) >> 16);
}

__device__ __forceinline__ float bf2f(u16 h) {
  return __uint_as_float(((unsigned)h) << 16);
}

__global__ __launch_bounds__(256) void zero_ws(unsigned* __restrict__ ghist,
                                               unsigned* __restrict__ counter) {
  int t = blockIdx.x * blockDim.x + threadIdx.x;
  if (t < 4096) ghist[t] = 0;
  if (t == 0) *counter = 0;
}

// ---------------- MLP layer: Y[rows,256] = act(X[rows,K] @ W[K,256] + b) ----------------
// block = 16 rows x 256 cols. Thread owns 4 rows x 4 cols: per d-quad only 4 broadcast
// ds_read_b128 (x) + 4 float4 W loads; per-output fmaf chain order identical to the
// bitwise-exact previous version (d, d+1, d+2, d+3 sequential over K).
template <int K, bool RELU, bool EMIT>
__global__ __launch_bounds__(256) void mlp_layer(const float* __restrict__ X,
                                                 const float* __restrict__ W,
                                                 const float* __restrict__ bias,
                                                 float* __restrict__ Y,
                                                 u16* __restrict__ hi,
                                                 u16* __restrict__ lo) {
  __shared__ float Xs[16 * K];
  const int t = threadIdx.x;
  const int row0 = blockIdx.x * 16;
  for (int f = t; f < 4 * K; f += 256) {  // 16*K/4 float4s
    *(float4*)(Xs + f * 4) = *(const float4*)(X + (size_t)row0 * K + f * 4);
  }
  __syncthreads();
  const int cg = (t & 63) * 4;  // column base (0..252)
  const int rg = (t >> 6) * 4;  // local row base (0,4,8,12)
  float acc[4][4];
#pragma unroll
  for (int r = 0; r < 4; r++)
#pragma unroll
    for (int c = 0; c < 4; c++) acc[r][c] = 0.f;

  for (int d = 0; d < K; d += 4) {
    float4 w0 = *(const float4*)(W + (d + 0) * H_DIM + cg);
    float4 w1 = *(const float4*)(W + (d + 1) * H_DIM + cg);
    float4 w2 = *(const float4*)(W + (d + 2) * H_DIM + cg);
    float4 w3 = *(const float4*)(W + (d + 3) * H_DIM + cg);
#pragma unroll
    for (int r = 0; r < 4; r++) {
      float4 x = *(const float4*)(Xs + (rg + r) * K + d);  // wave-uniform broadcast
#pragma unroll
      for (int c = 0; c < 4; c++) {
        float a = acc[r][c];
        a = fmaf(x.x, ((const float*)&w0)[c], a);
        a = fmaf(x.y, ((const float*)&w1)[c], a);
        a = fmaf(x.z, ((const float*)&w2)[c], a);
        a = fmaf(x.w, ((const float*)&w3)[c], a);
        acc[r][c] = a;
      }
    }
  }
  const float4 bv = *(const float4*)(bias + cg);
#pragma unroll
  for (int r = 0; r < 4; r++) {
    float4 v;
    v.x = acc[r][0] + bv.x;
    v.y = acc[r][1] + bv.y;
    v.z = acc[r][2] + bv.z;
    v.w = acc[r][3] + bv.w;
    if (RELU) {
      v.x = fmaxf(v.x, 0.f);
      v.y = fmaxf(v.y, 0.f);
      v.z = fmaxf(v.z, 0.f);
      v.w = fmaxf(v.w, 0.f);
    }
    const size_t grow = (size_t)(row0 + rg + r);
    *(float4*)(Y + grow * H_DIM + cg) = v;
    if (EMIT) {
      ushort4 hv, lv;
      hv.x = f2bf_rne(v.x); lv.x = f2bf_rne(v.x - bf2f(hv.x));
      hv.y = f2bf_rne(v.y); lv.y = f2bf_rne(v.y - bf2f(hv.y));
      hv.z = f2bf_rne(v.z); lv.z = f2bf_rne(v.z - bf2f(hv.z));
      hv.w = f2bf_rne(v.w); lv.w = f2bf_rne(v.w - bf2f(hv.w));
      *(ushort4*)(hi + grow * H_DIM + cg) = hv;
      *(ushort4*)(lo + grow * H_DIM + cg) = lv;
    }
  }
}

// ---------------- big GEMM (bf16x3 MFMA): C = Ah*Bh^T + Ah*Bl^T + Al*Bh^T, fused histogram ----
// 128x128 tile, 256 threads (4 waves of 64x64), BK=32. Interleaved phases: stage
// Ah/Al/Bh/Bl tiles once per k-chunk, 48 MFMAs per staging, double-buffered
// (T3-minimum 2-phase recipe: STAGE next -> ds_read cur -> MFMA -> one barrier).
// Epilogue goes through LDS for full-cacheline float4 C stores (no write-allocate fetch).
__global__ __launch_bounds__(256, 2) void gemm_sim_mfma(const u16* __restrict__ Ah,
                                                        const u16* __restrict__ Al,
                                                        const u16* __restrict__ Bh,
                                                        const u16* __restrict__ Bl,
                                                        float* __restrict__ C,
                                                        unsigned* __restrict__ ghist) {
  // buffer layout (u16 elems): [Ah 128x32 | Al | Bh | Bl] = 16384 elems = 32KB, x2 bufs
  __shared__ __align__(16) u16 SB[2 * 16384];  // 64KB
  __shared__ unsigned hist[4096];              // 16KB (total 80KB -> 2 blocks/CU)
  const int t = threadIdx.x;
  const int wave = t >> 6, lane = t & 63;
  // XCD swizzle: 4096 blocks, 8 XCDs -> each XCD gets 8 contiguous tile-rows
  const int bid = blockIdx.x;
  const int swz = (bid & 7) * 512 + (bid >> 3);
  const int m0 = (swz >> 6) * 128, n0 = (swz & 63) * 128;
  for (int i = t; i < 4096; i += 256) hist[i] = 0;

  f32x4 acc[4][4];
#pragma unroll
  for (int i = 0; i < 4; i++)
#pragma unroll
    for (int j = 0; j < 4; j++) acc[i][j] = (f32x4){0.f, 0.f, 0.f, 0.f};

  const int wm = wave >> 1, wn = wave & 1;
  // staging: per 8KB tile, 512 chunks of 16B; wave w covers chunks [w*128, +128) via 2 instrs
  const int c0 = wave * 128 + lane, c1 = c0 + 64;
  const int rA0 = c0 >> 2, ko0 = (c0 & 3) * 8;
  const int rA1 = c1 >> 2, ko1 = (c1 & 3) * 8;
  const int lrow = lane & 15, rq = lane >> 4;
  const int fa = (wm * 64 + lrow) * 32 + rq * 8;
  const int fb = (wn * 64 + lrow) * 32 + rq * 8;

  auto STAGE = [&](int b, int kc) {
    u16* d0 = SB + b * 16384 + wave * 1024;  // wave-uniform LDS base (2048B per wave)
    const size_t ga0 = (size_t)(m0 + rA0) * H_DIM + kc + ko0;
    const size_t ga1 = (size_t)(m0 + rA1) * H_DIM + kc + ko1;
    const size_t gb0 = (size_t)(n0 + rA0) * H_DIM + kc + ko0;
    const size_t gb1 = (size_t)(n0 + rA1) * H_DIM + kc + ko1;
    __builtin_amdgcn_global_load_lds((glb_u32*)(Ah + ga0), (lds_u32*)(d0), 16, 0, 0);
    __builtin_amdgcn_global_load_lds((glb_u32*)(Ah + ga1), (lds_u32*)(d0 + 512), 16, 0, 0);
    __builtin_amdgcn_global_load_lds((glb_u32*)(Al + ga0), (lds_u32*)(d0 + 4096), 16, 0, 0);
    __builtin_amdgcn_global_load_lds((glb_u32*)(Al + ga1), (lds_u32*)(d0 + 4608), 16, 0, 0);
    __builtin_amdgcn_global_load_lds((glb_u32*)(Bh + gb0), (lds_u32*)(d0 + 8192), 16, 0, 0);
    __builtin_amdgcn_global_load_lds((glb_u32*)(Bh + gb1), (lds_u32*)(d0 + 8704), 16, 0, 0);
    __builtin_amdgcn_global_load_lds((glb_u32*)(Bl + gb0), (lds_u32*)(d0 + 12288), 16, 0, 0);
    __builtin_amdgcn_global_load_lds((glb_u32*)(Bl + gb1), (lds_u32*)(d0 + 12800), 16, 0, 0);
  };

  int cur = 0;
  STAGE(0, 0);
  __syncthreads();  // drains vmcnt: buf0 ready
  for (int it = 0; it < 8; ++it) {
    if (it < 7) STAGE(cur ^ 1, (it + 1) * 32);  // prefetch next k-chunk
    const u16* B0 = SB + cur * 16384;
    bf16x8 aH[4], aL[4], bH[4], bL[4];
#pragma unroll
    for (int i = 0; i < 4; i++) {
      aH[i] = *(const bf16x8*)(B0 + fa + i * 512);
      aL[i] = *(const bf16x8*)(B0 + 4096 + fa + i * 512);
      bH[i] = *(const bf16x8*)(B0 + 8192 + fb + i * 512);
      bL[i] = *(const bf16x8*)(B0 + 12288 + fb + i * 512);
    }
#pragma unroll
    for (int i = 0; i < 4; i++)
#pragma unroll
      for (int j = 0; j < 4; j++)
        acc[i][j] = __builtin_amdgcn_mfma_f32_16x16x32_bf16(aH[i], bH[j], acc[i][j], 0, 0, 0);
#pragma unroll
    for (int i = 0; i < 4; i++)
#pragma unroll
      for (int j = 0; j < 4; j++)
        acc[i][j] = __builtin_amdgcn_mfma_f32_16x16x32_bf16(aH[i], bL[j], acc[i][j], 0, 0, 0);
#pragma unroll
    for (int i = 0; i < 4; i++)
#pragma unroll
      for (int j = 0; j < 4; j++)
        acc[i][j] = __builtin_amdgcn_mfma_f32_16x16x32_bf16(aL[i], bH[j], acc[i][j], 0, 0, 0);
    __syncthreads();  // drains vmcnt(0): next buf staged; all waves done reading cur
    cur ^= 1;
  }

  // epilogue: C/D layout col=lane&15, row=(lane>>4)*4+reg (m89-verified).
  // Stage 32-row chunks through LDS (reuses SB) for full-line float4 stores.
  float* Ct = (float*)SB;  // [32][128] fp32 = 16KB
#pragma unroll
  for (int c = 0; c < 4; ++c) {
    if (wm == (c >> 1)) {
      const int ib = 2 * (c & 1);
#pragma unroll
      for (int ii = 0; ii < 2; ++ii)
#pragma unroll
        for (int j = 0; j < 4; ++j)
#pragma unroll
          for (int q = 0; q < 4; ++q)
            Ct[(ii * 16 + rq * 4 + q) * 128 + wn * 64 + lrow + j * 16] = acc[ib + ii][j][q];
    }
    __syncthreads();
    const float4* Ct4 = (const float4*)Ct;
#pragma unroll
    for (int u = 0; u < 4; ++u) {
      const int f4 = t + u * 256;          // 1024 float4 = 32x128 floats
      const int row = f4 >> 5, col4 = f4 & 31;
      float4 v = Ct4[f4];
      *(float4*)(C + (size_t)(m0 + c * 32 + row) * NCOL + n0 + col4 * 4) = v;
      atomicAdd(&hist[fkey(v.x) >> 20], 1u);
      atomicAdd(&hist[fkey(v.y) >> 20], 1u);
      atomicAdd(&hist[fkey(v.z) >> 20], 1u);
      atomicAdd(&hist[fkey(v.w) >> 20], 1u);
    }
    __syncthreads();
  }
  for (int bq = t; bq < 4096; bq += 256) {
    unsigned cc = hist[bq];
    if (cc) atomicAdd(&ghist[bq], cc);
  }
}

// ---------------- threshold: smallest bin b* s.t. count(key >= b*<<20) >= TOPK ----------------
__global__ __launch_bounds__(256) void find_thresh(const unsigned* __restrict__ ghist,
                                                   unsigned* __restrict__ thresh) {
  __shared__ unsigned part[256];
  const int t = threadIdx.x;
  unsigned s = 0;
#pragma unroll
  for (int b = 0; b < 16; b++) s += ghist[t * 16 + b];
  part[t] = s;
  __syncthreads();
  if (t == 0) {
    unsigned cum = 0;
    int g = 255;
    for (; g > 0; g--) {
      if (cum + part[g] >= TOPK) break;
      cum += part[g];
    }
    int bsel = g * 16;
    for (int b = g * 16 + 15; b >= g * 16; b--) {
      cum += ghist[b];
      if (cum >= TOPK) { bsel = b; break; }
    }
    *thresh = (unsigned)bsel << 20;
  }
}

// ---------------- collect candidates >= threshold (with margin), recompute EXACT fp32 value ----
// Exact recompute = sequential fmaf over k=0..255, identical order to the fp32 path that
// matched the reference bitwise -> topk ordering is exact.
__device__ __forceinline__ void cand_push(unsigned kapprox, unsigned thr_m, unsigned idx,
                                          const float* __restrict__ m0f,
                                          const float* __restrict__ m1f,
                                          unsigned long long* __restrict__ cand,
                                          unsigned* __restrict__ counter) {
  if (kapprox >= thr_m) {
    const unsigned row = idx >> 13;   // /8192
    const unsigned col = idx & 8191u; // %8192
    const float4* a4 = (const float4*)(m0f + (size_t)row * H_DIM);
    const float4* b4 = (const float4*)(m1f + (size_t)col * H_DIM);
    float v = 0.f;
#pragma unroll 8
    for (int k = 0; k < H_DIM / 4; k++) {
      float4 a = a4[k], b = b4[k];
      v = fmaf(a.x, b.x, v);
      v = fmaf(a.y, b.y, v);
      v = fmaf(a.z, b.z, v);
      v = fmaf(a.w, b.w, v);
    }
    unsigned p = atomicAdd(counter, 1u);
    if (p < CAND_CAP)
      cand[p] = ((unsigned long long)fkey(v) << 32) |
                (unsigned long long)(0xFFFFFFFFu - idx);
  }
}

__global__ __launch_bounds__(256) void collect(const float* __restrict__ sim,
                                               const unsigned* __restrict__ thresh,
                                               const float* __restrict__ m0f,
                                               const float* __restrict__ m1f,
                                               unsigned long long* __restrict__ cand,
                                               unsigned* __restrict__ counter) {
  const unsigned thr = *thresh;
  // 4096-key margin (~0.03 at sim scale) > 2x observed bf16x3 absmax (0.0156):
  // guarantees the true top-512 survive approx-key thresholding.
  const unsigned thr_m = thr > 4096u ? thr - 4096u : 0u;
  const int stride = gridDim.x * blockDim.x;
  const int total4 = (NCOL * NCOL) / 4;  // 16,777,216
  const float4* s4 = (const float4*)sim;
  for (int i = blockIdx.x * blockDim.x + threadIdx.x; i < total4; i += stride) {
    float4 v = s4[i];
    unsigned base = (unsigned)i * 4u;
    cand_push(fkey(v.x), thr_m, base + 0u, m0f, m1f, cand, counter);
    cand_push(fkey(v.y), thr_m, base + 1u, m0f, m1f, cand, counter);
    cand_push(fkey(v.z), thr_m, base + 2u, m0f, m1f, cand, counter);
    cand_push(fkey(v.w), thr_m, base + 3u, m0f, m1f, cand, counter);
  }
}

// ---------------- single-block bitonic sort of candidates, write top-512 (row,col) as floats ----
__global__ __launch_bounds__(1024) void sort_topk(const unsigned long long* __restrict__ cand,
                                                  const unsigned* __restrict__ counter,
                                                  float* __restrict__ out) {
  __shared__ unsigned long long s[CAND_CAP];  // 64KB
  const int t = threadIdx.x;
  int n = (int)min(*counter, (unsigned)CAND_CAP);
  int P = 512;
  while (P < n) P <<= 1;  // <= CAND_CAP
  for (int i = t; i < P; i += 1024) s[i] = (i < n) ? cand[i] : 0ULL;
  __syncthreads();
  for (int k = 2; k <= P; k <<= 1) {
    for (int j = k >> 1; j > 0; j >>= 1) {
      for (int i = t; i < P; i += 1024) {
        int l = i ^ j;
        if (l > i) {
          bool desc = ((i & k) == 0);
          unsigned long long a = s[i], b = s[l];
          bool sw = desc ? (a < b) : (a > b);
          if (sw) { s[i] = b; s[l] = a; }
        }
      }
      __syncthreads();
    }
  }
  if (t < TOPK) {
    unsigned long long c = s[t];
    unsigned idx = 0xFFFFFFFFu - (unsigned)(c & 0xFFFFFFFFull);
    unsigned row = idx >> 13;        // /8192
    unsigned col = idx & 8191u;      // %8192
    out[t * 2 + 0] = (float)row;
    out[t * 2 + 1] = (float)col;
  }
}

extern "C" void kernel_launch(void* const* d_in, const int* in_sizes, int n_in,
                              void* d_out, int out_size, void* d_ws, size_t ws_size,
                              hipStream_t stream) {
  const float* desc0 = (const float*)d_in[0];
  const float* desc1 = (const float*)d_in[1];
  const float* W0a = (const float*)d_in[2];
  const float* b0a = (const float*)d_in[3];
  const float* W0b = (const float*)d_in[4];
  const float* b0b = (const float*)d_in[5];
  const float* W1a = (const float*)d_in[6];
  const float* b1a = (const float*)d_in[7];
  const float* W1b = (const float*)d_in[8];
  const float* b1b = (const float*)d_in[9];

  char* ws = (char*)d_ws;
  unsigned* ghist = (unsigned*)ws;                                  // 16KB
  unsigned* counter = (unsigned*)(ws + 16384);                     // 4B
  unsigned* thresh = (unsigned*)(ws + 16388);                      // 4B
  unsigned long long* cand = (unsigned long long*)(ws + 16448);    // 64KB
  float* mdesc0f = (float*)(ws + 131072);                          // 8MB fp32 (exact recompute)
  float* mdesc1f = mdesc0f + 8192 * 256;                           // 8MB
  float* hbuf = mdesc1f + 8192 * 256;                              // 8MB
  u16* Ahh = (u16*)(hbuf + 8192 * 256);                            // 4MB bf16 hi
  u16* All = Ahh + 8192 * 256;                                     // 4MB bf16 lo
  u16* Bhh = All + 8192 * 256;                                     // 4MB
  u16* Bll = Bhh + 8192 * 256;                                     // 4MB  (total ~40MB)

  float* outf = (float*)d_out;
  float* sim = outf + TOPK * 2;  // sim at float offset 1024 (16B aligned)

  zero_ws<<<16, 256, 0, stream>>>(ghist, counter);

  mlp_layer<128, true, false><<<512, 256, 0, stream>>>(desc0, W0a, b0a, hbuf, nullptr, nullptr);
  mlp_layer<256, false, true><<<512, 256, 0, stream>>>(hbuf, W0b, b0b, mdesc0f, Ahh, All);
  mlp_layer<128, true, false><<<512, 256, 0, stream>>>(desc1, W1a, b1a, hbuf, nullptr, nullptr);
  mlp_layer<256, false, true><<<512, 256, 0, stream>>>(hbuf, W1b, b1b, mdesc1f, Bhh, Bll);

  gemm_sim_mfma<<<4096, 256, 0, stream>>>(Ahh, All, Bhh, Bll, sim, ghist);
  find_thresh<<<1, 256, 0, stream>>>(ghist, thresh);
  collect<<<4096, 256, 0, stream>>>(sim, thresh, mdesc0f, mdesc1f, cand, counter);
  sort_topk<<<1, 1024, 0, stream>>>(cand, counter, outf);
}

// Round 3
// 659.213 us; speedup vs baseline: 1.0609x; 1.0609x over previous
//
#include <hip/hip_runtime.h>
#include <stdint.h>

#define H_DIM 256
#define NCOL 8192
#define TOPK 512
#define CAND_CAP 8192

typedef unsigned short u16;
typedef __attribute__((ext_vector_type(8))) __bf16 bf16x8;
typedef __attribute__((ext_vector_type(4))) float f32x4;
typedef unsigned __attribute__((address_space(3))) lds_u32;
typedef const unsigned __attribute__((address_space(1))) glb_u32;

// monotonic float -> uint key (order-preserving for all finite floats)
__device__ __forceinline__ unsigned fkey(float f) {
  unsigned u = __float_as_uint(f);
  unsigned m = (unsigned)((int)u >> 31) | 0x80000000u;
  return u ^ m;
}

__device__ __forceinline__ u16 f2bf_rne(float f) {
  unsigned u = __float_as_uint(f);
  return (u16)((u + 0x7fffu + ((u >> 16) & 1u)) >> 16);
}

__device__ __forceinline__ float bf2f(u16 h) {
  return __uint_as_float(((unsigned)h) << 16);
}

__global__ __launch_bounds__(256) void zero_ws(unsigned* __restrict__ ghist,
                                               unsigned* __restrict__ counter) {
  int t = blockIdx.x * blockDim.x + threadIdx.x;
  if (t < 4096) ghist[t] = 0;
  if (t == 0) *counter = 0;
}

// ---------------- MLP layer: Y[rows,256] = act(X[rows,K] @ W[K,256] + b) ----------------
template <int K, bool RELU, bool EMIT>
__global__ __launch_bounds__(256) void mlp_layer(const float* __restrict__ X,
                                                 const float* __restrict__ W,
                                                 const float* __restrict__ bias,
                                                 float* __restrict__ Y,
                                                 u16* __restrict__ hi,
                                                 u16* __restrict__ lo) {
  __shared__ float Xs[16 * K];
  const int t = threadIdx.x;
  const int row0 = blockIdx.x * 16;
  for (int f = t; f < 4 * K; f += 256) {  // 16*K/4 float4s
    *(float4*)(Xs + f * 4) = *(const float4*)(X + (size_t)row0 * K + f * 4);
  }
  __syncthreads();
  const int cg = (t & 63) * 4;  // column base (0..252)
  const int rg = (t >> 6) * 4;  // local row base (0,4,8,12)
  float acc[4][4];
#pragma unroll
  for (int r = 0; r < 4; r++)
#pragma unroll
    for (int c = 0; c < 4; c++) acc[r][c] = 0.f;

  for (int d = 0; d < K; d += 4) {
    float4 w0 = *(const float4*)(W + (d + 0) * H_DIM + cg);
    float4 w1 = *(const float4*)(W + (d + 1) * H_DIM + cg);
    float4 w2 = *(const float4*)(W + (d + 2) * H_DIM + cg);
    float4 w3 = *(const float4*)(W + (d + 3) * H_DIM + cg);
#pragma unroll
    for (int r = 0; r < 4; r++) {
      float4 x = *(const float4*)(Xs + (rg + r) * K + d);  // wave-uniform broadcast
#pragma unroll
      for (int c = 0; c < 4; c++) {
        float a = acc[r][c];
        a = fmaf(x.x, ((const float*)&w0)[c], a);
        a = fmaf(x.y, ((const float*)&w1)[c], a);
        a = fmaf(x.z, ((const float*)&w2)[c], a);
        a = fmaf(x.w, ((const float*)&w3)[c], a);
        acc[r][c] = a;
      }
    }
  }
  const float4 bv = *(const float4*)(bias + cg);
#pragma unroll
  for (int r = 0; r < 4; r++) {
    float4 v;
    v.x = acc[r][0] + bv.x;
    v.y = acc[r][1] + bv.y;
    v.z = acc[r][2] + bv.z;
    v.w = acc[r][3] + bv.w;
    if (RELU) {
      v.x = fmaxf(v.x, 0.f);
      v.y = fmaxf(v.y, 0.f);
      v.z = fmaxf(v.z, 0.f);
      v.w = fmaxf(v.w, 0.f);
    }
    const size_t grow = (size_t)(row0 + rg + r);
    *(float4*)(Y + grow * H_DIM + cg) = v;
    if (EMIT) {
      ushort4 hv, lv;
      hv.x = f2bf_rne(v.x); lv.x = f2bf_rne(v.x - bf2f(hv.x));
      hv.y = f2bf_rne(v.y); lv.y = f2bf_rne(v.y - bf2f(hv.y));
      hv.z = f2bf_rne(v.z); lv.z = f2bf_rne(v.z - bf2f(hv.z));
      hv.w = f2bf_rne(v.w); lv.w = f2bf_rne(v.w - bf2f(hv.w));
      *(ushort4*)(hi + grow * H_DIM + cg) = hv;
      *(ushort4*)(lo + grow * H_DIM + cg) = lv;
    }
  }
}

// ---------------- big GEMM (bf16x3 as one K=768 MFMA GEMM), 8-phase counted-vmcnt ----------
// 256x256 tile, 512 threads (8 waves, 2M x 4N), BK=64, per-wave 128x64 output.
// K-tiles: 0-3 Ah*Bh, 4-7 Ah*Bl, 8-11 Al*Bh (all accumulate into the same acc).
// LDS 128KB: 2 buffers x (A 256x64 + B 256x64) bf16, XOR-swizzled (byte ^= (row&7)<<4)
// via inverse-swizzled global source (linear global_load_lds dest) + swizzled ds_read.
// Counted vmcnt(8): next tile's 8 staging loads stay in flight across barriers.
__global__ __launch_bounds__(512, 2) void gemm_sim_mfma(const u16* __restrict__ Ah,
                                                        const u16* __restrict__ Al,
                                                        const u16* __restrict__ Bh,
                                                        const u16* __restrict__ Bl,
                                                        float* __restrict__ C,
                                                        unsigned* __restrict__ ghist) {
  __shared__ __align__(16) char SB[131072];  // 2 x (32KB A + 32KB B)
  const int t = threadIdx.x;
  const int wave = t >> 6, lane = t & 63;
  const int wm = wave >> 2, wn = wave & 3;  // 2M x 4N waves
  // XCD swizzle: 1024 blocks, 1024%8==0 -> bijective
  const int bid = blockIdx.x;
  const int swz = (bid & 7) * 128 + (bid >> 3);
  const int m0 = (swz >> 5) * 256, n0 = (swz & 31) * 256;

  f32x4 acc[8][4];
#pragma unroll
  for (int i = 0; i < 8; i++)
#pragma unroll
    for (int j = 0; j < 4; j++) acc[i][j] = (f32x4){0.f, 0.f, 0.f, 0.f};

  // staging constants: round i covers LDS bytes [i*8192, +8192) of a 32KB tile region.
  // LDS byte b = i*8192 + t*16 -> row r = i*64 + (t>>3), col c = (t&7)*16.
  // swizzle s(r) = ((r&7)<<4); source col = c ^ s(r)  (involution; r&7 == (t>>3)&7)
  const int srow = t >> 3;                                    // + i*64
  const int scolE = ((t & 7) ^ (srow & 7)) << 3;              // source col in elems (x8)
  // fragment read constants: frag row lrow, k-subgroup byte kq16; swizzle uses lane&7
  const int lrow = lane & 15;
  const int kq16 = (lane >> 4) << 4;
  const int asz = (lrow & 7) << 4;

  auto STAGE = [&](int bsel, int tt) {
    const u16* pa = (tt < 8) ? Ah : Al;
    const u16* pb = (tt < 4) ? Bh : ((tt < 8) ? Bl : Bh);
    const int kofs = (tt & 3) * 64;
    char* base = SB + bsel * 65536;
    const size_t aoff = (size_t)(m0 + srow) * H_DIM + kofs + scolE;
    const size_t boff = (size_t)(n0 + srow) * H_DIM + kofs + scolE;
#pragma unroll
    for (int i = 0; i < 4; i++)
      __builtin_amdgcn_global_load_lds((glb_u32*)(pa + aoff + (size_t)i * 64 * H_DIM),
                                       (lds_u32*)(base + i * 8192 + wave * 1024), 16, 0, 0);
#pragma unroll
    for (int i = 0; i < 4; i++)
      __builtin_amdgcn_global_load_lds((glb_u32*)(pb + boff + (size_t)i * 64 * H_DIM),
                                       (lds_u32*)(base + 32768 + i * 8192 + wave * 1024), 16, 0, 0);
  };

  STAGE(0, 0);
  for (int tt = 0; tt < 12; ++tt) {
    if (tt + 1 < 12) {
      STAGE((tt + 1) & 1, tt + 1);
      asm volatile("s_waitcnt vmcnt(8)" ::: "memory");  // tile tt staged; tt+1 in flight
    } else {
      asm volatile("s_waitcnt vmcnt(0)" ::: "memory");  // last tile: full drain ok
    }
    __builtin_amdgcn_s_barrier();
    asm volatile("" ::: "memory");
    const char* bb = SB + (tt & 1) * 65536;
#pragma unroll
    for (int kk = 0; kk < 2; ++kk) {
      bf16x8 af[8], bfr[4];
#pragma unroll
      for (int fm = 0; fm < 8; fm++)
        af[fm] = *(const bf16x8*)(bb + (wm * 128 + fm * 16 + lrow) * 128 +
                                  ((kk * 64 + kq16) ^ asz));
#pragma unroll
      for (int fn = 0; fn < 4; fn++)
        bfr[fn] = *(const bf16x8*)(bb + 32768 + (wn * 64 + fn * 16 + lrow) * 128 +
                                   ((kk * 64 + kq16) ^ asz));
      __builtin_amdgcn_s_setprio(1);
#pragma unroll
      for (int fm = 0; fm < 8; fm++)
#pragma unroll
        for (int fn = 0; fn < 4; fn++)
          acc[fm][fn] =
              __builtin_amdgcn_mfma_f32_16x16x32_bf16(af[fm], bfr[fn], acc[fm][fn], 0, 0, 0);
      __builtin_amdgcn_s_setprio(0);
    }
    __builtin_amdgcn_s_barrier();  // all waves done reading buf[tt&1]
    asm volatile("" ::: "memory");
  }

  // ---------- epilogue: LDS-staged coalesced C-store + histogram ----------
  // C/D frag layout: col=lane&15, row=(lane>>4)*4+q (m89-verified).
  unsigned* hist = (unsigned*)SB;            // 16KB
  float* Ct = (float*)(SB + 16384);          // [64][260] fp32, pad 4 -> 66.5KB
  for (int i = t; i < 4096; i += 512) hist[i] = 0;
  __syncthreads();
#pragma unroll
  for (int ch = 0; ch < 4; ++ch) {  // 64-row chunks of the 256-row tile
    if (wm == (ch >> 1)) {
      const int fmb = (ch & 1) * 4;
#pragma unroll
      for (int fi = 0; fi < 4; fi++)
#pragma unroll
        for (int fn = 0; fn < 4; fn++)
#pragma unroll
          for (int q = 0; q < 4; q++)
            Ct[(fi * 16 + (lane >> 4) * 4 + q) * 260 + wn * 64 + fn * 16 + lrow] =
                acc[fmb + fi][fn][q];
    }
    __syncthreads();
#pragma unroll
    for (int u = 0; u < 8; ++u) {
      const int idx = t + u * 512;  // 4096 float4 = 64x256 floats
      const int row = idx >> 6, c4 = idx & 63;
      float4 v = *(const float4*)(Ct + row * 260 + c4 * 4);
      *(float4*)(C + (size_t)(m0 + ch * 64 + row) * NCOL + n0 + c4 * 4) = v;
      atomicAdd(&hist[fkey(v.x) >> 20], 1u);
      atomicAdd(&hist[fkey(v.y) >> 20], 1u);
      atomicAdd(&hist[fkey(v.z) >> 20], 1u);
      atomicAdd(&hist[fkey(v.w) >> 20], 1u);
    }
    __syncthreads();
  }
  for (int bq = t; bq < 4096; bq += 512) {
    unsigned cc = hist[bq];
    if (cc) atomicAdd(&ghist[bq], cc);
  }
}

// ---------------- threshold: smallest bin b* s.t. count(key >= b*<<20) >= TOPK ----------------
__global__ __launch_bounds__(256) void find_thresh(const unsigned* __restrict__ ghist,
                                                   unsigned* __restrict__ thresh) {
  __shared__ unsigned part[256];
  const int t = threadIdx.x;
  unsigned s = 0;
#pragma unroll
  for (int b = 0; b < 16; b++) s += ghist[t * 16 + b];
  part[t] = s;
  __syncthreads();
  if (t == 0) {
    unsigned cum = 0;
    int g = 255;
    for (; g > 0; g--) {
      if (cum + part[g] >= TOPK) break;
      cum += part[g];
    }
    int bsel = g * 16;
    for (int b = g * 16 + 15; b >= g * 16; b--) {
      cum += ghist[b];
      if (cum >= TOPK) { bsel = b; break; }
    }
    *thresh = (unsigned)bsel << 20;
  }
}

// ---------------- collect candidates >= threshold (with margin), recompute EXACT fp32 value ----
__device__ __forceinline__ void cand_push(unsigned kapprox, unsigned thr_m, unsigned idx,
                                          const float* __restrict__ m0f,
                                          const float* __restrict__ m1f,
                                          unsigned long long* __restrict__ cand,
                                          unsigned* __restrict__ counter) {
  if (kapprox >= thr_m) {
    const unsigned row = idx >> 13;   // /8192
    const unsigned col = idx & 8191u; // %8192
    const float4* a4 = (const float4*)(m0f + (size_t)row * H_DIM);
    const float4* b4 = (const float4*)(m1f + (size_t)col * H_DIM);
    float v = 0.f;
#pragma unroll 8
    for (int k = 0; k < H_DIM / 4; k++) {
      float4 a = a4[k], b = b4[k];
      v = fmaf(a.x, b.x, v);
      v = fmaf(a.y, b.y, v);
      v = fmaf(a.z, b.z, v);
      v = fmaf(a.w, b.w, v);
    }
    unsigned p = atomicAdd(counter, 1u);
    if (p < CAND_CAP)
      cand[p] = ((unsigned long long)fkey(v) << 32) |
                (unsigned long long)(0xFFFFFFFFu - idx);
  }
}

__global__ __launch_bounds__(256) void collect(const float* __restrict__ sim,
                                               const unsigned* __restrict__ thresh,
                                               const float* __restrict__ m0f,
                                               const float* __restrict__ m1f,
                                               unsigned long long* __restrict__ cand,
                                               unsigned* __restrict__ counter) {
  const unsigned thr = *thresh;
  // 4096-key margin (~0.03 at sim scale) > 2x observed bf16x3 absmax (0.0156)
  const unsigned thr_m = thr > 4096u ? thr - 4096u : 0u;
  const int stride = gridDim.x * blockDim.x;
  const int total4 = (NCOL * NCOL) / 4;  // 16,777,216
  const float4* s4 = (const float4*)sim;
  for (int i = blockIdx.x * blockDim.x + threadIdx.x; i < total4; i += stride) {
    float4 v = s4[i];
    unsigned base = (unsigned)i * 4u;
    cand_push(fkey(v.x), thr_m, base + 0u, m0f, m1f, cand, counter);
    cand_push(fkey(v.y), thr_m, base + 1u, m0f, m1f, cand, counter);
    cand_push(fkey(v.z), thr_m, base + 2u, m0f, m1f, cand, counter);
    cand_push(fkey(v.w), thr_m, base + 3u, m0f, m1f, cand, counter);
  }
}

// ---------------- single-block bitonic sort of candidates, write top-512 (row,col) ----------
__global__ __launch_bounds__(1024) void sort_topk(const unsigned long long* __restrict__ cand,
                                                  const unsigned* __restrict__ counter,
                                                  float* __restrict__ out) {
  __shared__ unsigned long long s[CAND_CAP];  // 64KB
  const int t = threadIdx.x;
  int n = (int)min(*counter, (unsigned)CAND_CAP);
  int P = 512;
  while (P < n) P <<= 1;  // <= CAND_CAP
  for (int i = t; i < P; i += 1024) s[i] = (i < n) ? cand[i] : 0ULL;
  __syncthreads();
  for (int k = 2; k <= P; k <<= 1) {
    for (int j = k >> 1; j > 0; j >>= 1) {
      for (int i = t; i < P; i += 1024) {
        int l = i ^ j;
        if (l > i) {
          bool desc = ((i & k) == 0);
          unsigned long long a = s[i], b = s[l];
          bool sw = desc ? (a < b) : (a > b);
          if (sw) { s[i] = b; s[l] = a; }
        }
      }
      __syncthreads();
    }
  }
  if (t < TOPK) {
    unsigned long long c = s[t];
    unsigned idx = 0xFFFFFFFFu - (unsigned)(c & 0xFFFFFFFFull);
    unsigned row = idx >> 13;        // /8192
    unsigned col = idx & 8191u;      // %8192
    out[t * 2 + 0] = (float)row;
    out[t * 2 + 1] = (float)col;
  }
}

extern "C" void kernel_launch(void* const* d_in, const int* in_sizes, int n_in,
                              void* d_out, int out_size, void* d_ws, size_t ws_size,
                              hipStream_t stream) {
  const float* desc0 = (const float*)d_in[0];
  const float* desc1 = (const float*)d_in[1];
  const float* W0a = (const float*)d_in[2];
  const float* b0a = (const float*)d_in[3];
  const float* W0b = (const float*)d_in[4];
  const float* b0b = (const float*)d_in[5];
  const float* W1a = (const float*)d_in[6];
  const float* b1a = (const float*)d_in[7];
  const float* W1b = (const float*)d_in[8];
  const float* b1b = (const float*)d_in[9];

  char* ws = (char*)d_ws;
  unsigned* ghist = (unsigned*)ws;                                  // 16KB
  unsigned* counter = (unsigned*)(ws + 16384);                     // 4B
  unsigned* thresh = (unsigned*)(ws + 16388);                      // 4B
  unsigned long long* cand = (unsigned long long*)(ws + 16448);    // 64KB
  float* mdesc0f = (float*)(ws + 131072);                          // 8MB fp32 (exact recompute)
  float* mdesc1f = mdesc0f + 8192 * 256;                           // 8MB
  float* hbuf = mdesc1f + 8192 * 256;                              // 8MB
  u16* Ahh = (u16*)(hbuf + 8192 * 256);                            // 4MB bf16 hi
  u16* All = Ahh + 8192 * 256;                                     // 4MB bf16 lo
  u16* Bhh = All + 8192 * 256;                                     // 4MB
  u16* Bll = Bhh + 8192 * 256;                                     // 4MB  (total ~40MB)

  float* outf = (float*)d_out;
  float* sim = outf + TOPK * 2;  // sim at float offset 1024 (16B aligned)

  zero_ws<<<16, 256, 0, stream>>>(ghist, counter);

  mlp_layer<128, true, false><<<512, 256, 0, stream>>>(desc0, W0a, b0a, hbuf, nullptr, nullptr);
  mlp_layer<256, false, true><<<512, 256, 0, stream>>>(hbuf, W0b, b0b, mdesc0f, Ahh, All);
  mlp_layer<128, true, false><<<512, 256, 0, stream>>>(desc1, W1a, b1a, hbuf, nullptr, nullptr);
  mlp_layer<256, false, true><<<512, 256, 0, stream>>>(hbuf, W1b, b1b, mdesc1f, Bhh, Bll);

  gemm_sim_mfma<<<1024, 512, 0, stream>>>(Ahh, All, Bhh, Bll, sim, ghist);
  find_thresh<<<1, 256, 0, stream>>>(ghist, thresh);
  collect<<<4096, 256, 0, stream>>>(sim, thresh, mdesc0f, mdesc1f, cand, counter);
  sort_topk<<<1, 1024, 0, stream>>>(cand, counter, outf);
}

// Round 4
// 568.402 us; speedup vs baseline: 1.2304x; 1.1598x over previous
//
#include <hip/hip_runtime.h>
#include <stdint.h>

#define H_DIM 256
#define NCOL 8192
#define TOPK 512
#define CAND_CAP 8192

typedef unsigned short u16;
typedef __attribute__((ext_vector_type(8))) __bf16 bf16x8;
typedef __attribute__((ext_vector_type(4))) float f32x4;
typedef unsigned __attribute__((address_space(3))) lds_u32;
typedef const unsigned __attribute__((address_space(1))) glb_u32;

// monotonic float -> uint key (order-preserving for all finite floats)
__device__ __forceinline__ unsigned fkey(float f) {
  unsigned u = __float_as_uint(f);
  unsigned m = (unsigned)((int)u >> 31) | 0x80000000u;
  return u ^ m;
}

__device__ __forceinline__ u16 f2bf_rne(float f) {
  unsigned u = __float_as_uint(f);
  return (u16)((u + 0x7fffu + ((u >> 16) & 1u)) >> 16);
}

__device__ __forceinline__ float bf2f(u16 h) {
  return __uint_as_float(((unsigned)h) << 16);
}

// ---------------- dual MLP layer: both descriptors in one launch (grid 1024) -----------
// blocks 0-511: set 0; 512-1023: set 1. block = 16 rows x 256 threads, thread owns 4x4.
// Per-output fmaf chain order (d,d+1,d+2,d+3 sequential over K) matches the bitwise-exact
// fp32 path used by the collect recompute.
template <int K, bool RELU, bool EMIT, bool ZERO>
__global__ __launch_bounds__(256) void mlp_dual(
    const float* __restrict__ X0, const float* __restrict__ W0,
    const float* __restrict__ bias0, float* __restrict__ Y0,
    u16* __restrict__ h0, u16* __restrict__ l0,
    const float* __restrict__ X1, const float* __restrict__ W1,
    const float* __restrict__ bias1, float* __restrict__ Y1,
    u16* __restrict__ h1, u16* __restrict__ l1,
    unsigned* __restrict__ ghist, unsigned* __restrict__ counter) {
  __shared__ float Xs[16 * K];
  const int t = threadIdx.x;
  if (ZERO && blockIdx.x == 0) {  // folded zero_ws (runs before gemm in stream order)
    for (int i = t; i < 4096; i += 256) ghist[i] = 0;
    if (t == 0) *counter = 0;
  }
  const int half = blockIdx.x >> 9;
  const float* X = half ? X1 : X0;
  const float* W = half ? W1 : W0;
  const float* bias = half ? bias1 : bias0;
  float* Y = half ? Y1 : Y0;
  u16* hi = half ? h1 : h0;
  u16* lo = half ? l1 : l0;
  const int row0 = (blockIdx.x & 511) * 16;

  for (int f = t; f < 4 * K; f += 256) {  // 16*K/4 float4s
    *(float4*)(Xs + f * 4) = *(const float4*)(X + (size_t)row0 * K + f * 4);
  }
  __syncthreads();
  const int cg = (t & 63) * 4;  // column base (0..252)
  const int rg = (t >> 6) * 4;  // local row base (0,4,8,12)
  float acc[4][4];
#pragma unroll
  for (int r = 0; r < 4; r++)
#pragma unroll
    for (int c = 0; c < 4; c++) acc[r][c] = 0.f;

  for (int d = 0; d < K; d += 4) {
    float4 w0 = *(const float4*)(W + (d + 0) * H_DIM + cg);
    float4 w1 = *(const float4*)(W + (d + 1) * H_DIM + cg);
    float4 w2 = *(const float4*)(W + (d + 2) * H_DIM + cg);
    float4 w3 = *(const float4*)(W + (d + 3) * H_DIM + cg);
#pragma unroll
    for (int r = 0; r < 4; r++) {
      float4 x = *(const float4*)(Xs + (rg + r) * K + d);  // wave-uniform broadcast
#pragma unroll
      for (int c = 0; c < 4; c++) {
        float a = acc[r][c];
        a = fmaf(x.x, ((const float*)&w0)[c], a);
        a = fmaf(x.y, ((const float*)&w1)[c], a);
        a = fmaf(x.z, ((const float*)&w2)[c], a);
        a = fmaf(x.w, ((const float*)&w3)[c], a);
        acc[r][c] = a;
      }
    }
  }
  const float4 bv = *(const float4*)(bias + cg);
#pragma unroll
  for (int r = 0; r < 4; r++) {
    float4 v;
    v.x = acc[r][0] + bv.x;
    v.y = acc[r][1] + bv.y;
    v.z = acc[r][2] + bv.z;
    v.w = acc[r][3] + bv.w;
    if (RELU) {
      v.x = fmaxf(v.x, 0.f);
      v.y = fmaxf(v.y, 0.f);
      v.z = fmaxf(v.z, 0.f);
      v.w = fmaxf(v.w, 0.f);
    }
    const size_t grow = (size_t)(row0 + rg + r);
    *(float4*)(Y + grow * H_DIM + cg) = v;
    if (EMIT) {
      ushort4 hv, lv;
      hv.x = f2bf_rne(v.x); lv.x = f2bf_rne(v.x - bf2f(hv.x));
      hv.y = f2bf_rne(v.y); lv.y = f2bf_rne(v.y - bf2f(hv.y));
      hv.z = f2bf_rne(v.z); lv.z = f2bf_rne(v.z - bf2f(hv.z));
      hv.w = f2bf_rne(v.w); lv.w = f2bf_rne(v.w - bf2f(hv.w));
      *(ushort4*)(hi + grow * H_DIM + cg) = hv;
      *(ushort4*)(lo + grow * H_DIM + cg) = lv;
    }
  }
}

// ---------------- big GEMM (bf16x3), operand-interleaved 8-chunk counted-vmcnt ----------
// 256x256 tile, 512 threads (8 waves, 2M x 4N), per-wave 128x64 output.
// K-chunks of 32; per chunk stage [Ah|Al] and [Bh|Bl] interleaved per row: LDS row =
// 128B [Xh(32 bf16) | Xl(32 bf16)], XOR-swizzled byte ^= ((row&7)<<4) across all 8 slots
// (conflict-free ds_read_b128) applied via inverse-swizzled PER-LANE global source
// (linear global_load_lds dest, rule #21). Each panel staged exactly ONCE (512KB/block).
// 96 MFMA per barrier-pair, counted vmcnt(8) keeps next chunk's loads in flight.
__global__ __launch_bounds__(512, 2) void gemm_sim_mfma(const u16* __restrict__ Ah,
                                                        const u16* __restrict__ Al,
                                                        const u16* __restrict__ Bh,
                                                        const u16* __restrict__ Bl,
                                                        float* __restrict__ C,
                                                        unsigned* __restrict__ ghist) {
  __shared__ __align__(16) char SB[131072];  // 2 bufs x (A2 32KB + B2 32KB)
  const int t = threadIdx.x;
  const int wave = t >> 6, lane = t & 63;
  const int wm = wave >> 2, wn = wave & 3;  // 2M x 4N waves
  // XCD swizzle: 1024 blocks, 1024%8==0 -> bijective
  const int bid = blockIdx.x;
  const int swz = (bid & 7) * 128 + (bid >> 3);
  const int m0 = (swz >> 5) * 256, n0 = (swz & 31) * 256;

  f32x4 acc[8][4];
#pragma unroll
  for (int i = 0; i < 8; i++)
#pragma unroll
    for (int j = 0; j < 4; j++) acc[i][j] = (f32x4){0.f, 0.f, 0.f, 0.f};

  // staging: round i covers LDS bytes [i*8192,+8192): row = i*64 + (t>>3), slot = t&7.
  // source slot = slot ^ (row&7) (involution); slots 0-3 -> Xh col16 slot, 4-7 -> Xl.
  const int srow8 = t >> 3;
  const int sA = (t & 7) ^ (srow8 & 7);
  const u16* pAsrc = (sA < 4) ? Ah : Al;
  const u16* pBsrc = (sA < 4) ? Bh : Bl;
  const int scolE = (sA & 3) * 8;  // elems within the 32-elem k-chunk
  // fragment read: row lrow in 16-row group, k-group byte kq16; swizzle key = lrow&7
  const int lrow = lane & 15;
  const int kq16 = (lane >> 4) << 4;
  const int asz = (lrow & 7) << 4;
  const int cH = kq16 ^ asz;          // hi operand col byte within 128B row
  const int cL = (64 + kq16) ^ asz;   // lo operand col byte

  auto STAGE = [&](int bsel, int tt) {
    const int kofs = tt * 32;
    char* base = SB + bsel * 65536;
    const size_t ar = (size_t)(m0 + srow8) * H_DIM + kofs + scolE;
    const size_t br = (size_t)(n0 + srow8) * H_DIM + kofs + scolE;
#pragma unroll
    for (int i = 0; i < 4; i++)
      __builtin_amdgcn_global_load_lds((glb_u32*)(pAsrc + ar + (size_t)i * 64 * H_DIM),
                                       (lds_u32*)(base + i * 8192 + wave * 1024), 16, 0, 0);
#pragma unroll
    for (int i = 0; i < 4; i++)
      __builtin_amdgcn_global_load_lds((glb_u32*)(pBsrc + br + (size_t)i * 64 * H_DIM),
                                       (lds_u32*)(base + 32768 + i * 8192 + wave * 1024), 16, 0, 0);
  };

  STAGE(0, 0);
  for (int tt = 0; tt < 8; ++tt) {
    if (tt < 7) {
      STAGE((tt + 1) & 1, tt + 1);
      asm volatile("s_waitcnt vmcnt(8)" ::: "memory");  // chunk tt staged; tt+1 in flight
    } else {
      asm volatile("s_waitcnt vmcnt(0)" ::: "memory");
    }
    __builtin_amdgcn_s_barrier();
    asm volatile("" ::: "memory");
    const char* bb = SB + (tt & 1) * 65536;
    const char* bA = bb + (wm * 128 + lrow) * 128;
    const char* bB = bb + 32768 + (wn * 64 + lrow) * 128;
    // sub-phase 1: Ah x Bh
    bf16x8 aH[8], bH[4];
#pragma unroll
    for (int fm = 0; fm < 8; fm++) aH[fm] = *(const bf16x8*)(bA + fm * 2048 + cH);
#pragma unroll
    for (int fn = 0; fn < 4; fn++) bH[fn] = *(const bf16x8*)(bB + fn * 2048 + cH);
    __builtin_amdgcn_s_setprio(1);
#pragma unroll
    for (int fm = 0; fm < 8; fm++)
#pragma unroll
      for (int fn = 0; fn < 4; fn++)
        acc[fm][fn] = __builtin_amdgcn_mfma_f32_16x16x32_bf16(aH[fm], bH[fn], acc[fm][fn], 0, 0, 0);
    __builtin_amdgcn_s_setprio(0);
    // sub-phase 2: Ah x Bl (aH live)
    {
      bf16x8 bL[4];
#pragma unroll
      for (int fn = 0; fn < 4; fn++) bL[fn] = *(const bf16x8*)(bB + fn * 2048 + cL);
      __builtin_amdgcn_s_setprio(1);
#pragma unroll
      for (int fm = 0; fm < 8; fm++)
#pragma unroll
        for (int fn = 0; fn < 4; fn++)
          acc[fm][fn] = __builtin_amdgcn_mfma_f32_16x16x32_bf16(aH[fm], bL[fn], acc[fm][fn], 0, 0, 0);
      __builtin_amdgcn_s_setprio(0);
    }
    // sub-phase 3: Al x Bh (bH live)
    {
      bf16x8 aL[8];
#pragma unroll
      for (int fm = 0; fm < 8; fm++) aL[fm] = *(const bf16x8*)(bA + fm * 2048 + cL);
      __builtin_amdgcn_s_setprio(1);
#pragma unroll
      for (int fm = 0; fm < 8; fm++)
#pragma unroll
        for (int fn = 0; fn < 4; fn++)
          acc[fm][fn] = __builtin_amdgcn_mfma_f32_16x16x32_bf16(aL[fm], bH[fn], acc[fm][fn], 0, 0, 0);
      __builtin_amdgcn_s_setprio(0);
    }
    __builtin_amdgcn_s_barrier();  // all waves done reading buf[tt&1]
    asm volatile("" ::: "memory");
  }

  // ---------- epilogue: LDS-staged coalesced C-store + histogram ----------
  // C/D frag layout: col=lane&15, row=(lane>>4)*4+q (m89-verified).
  unsigned* hist = (unsigned*)SB;    // 16KB
  float* Ct = (float*)(SB + 16384);  // [64][260] fp32, pad 4
  for (int i = t; i < 4096; i += 512) hist[i] = 0;
  __syncthreads();
#pragma unroll
  for (int ch = 0; ch < 4; ++ch) {  // 64-row chunks of the 256-row tile
    if (wm == (ch >> 1)) {
      const int fmb = (ch & 1) * 4;
#pragma unroll
      for (int fi = 0; fi < 4; fi++)
#pragma unroll
        for (int fn = 0; fn < 4; fn++)
#pragma unroll
          for (int q = 0; q < 4; q++)
            Ct[(fi * 16 + (lane >> 4) * 4 + q) * 260 + wn * 64 + fn * 16 + lrow] =
                acc[fmb + fi][fn][q];
    }
    __syncthreads();
#pragma unroll
    for (int u = 0; u < 8; ++u) {
      const int idx = t + u * 512;  // 4096 float4 = 64x256 floats
      const int row = idx >> 6, c4 = idx & 63;
      float4 v = *(const float4*)(Ct + row * 260 + c4 * 4);
      *(float4*)(C + (size_t)(m0 + ch * 64 + row) * NCOL + n0 + c4 * 4) = v;
      atomicAdd(&hist[fkey(v.x) >> 20], 1u);
      atomicAdd(&hist[fkey(v.y) >> 20], 1u);
      atomicAdd(&hist[fkey(v.z) >> 20], 1u);
      atomicAdd(&hist[fkey(v.w) >> 20], 1u);
    }
    __syncthreads();
  }
  for (int bq = t; bq < 4096; bq += 512) {
    unsigned cc = hist[bq];
    if (cc) atomicAdd(&ghist[bq], cc);
  }
}

// ---------------- threshold: smallest bin b* s.t. count(key >= b*<<20) >= TOPK ----------------
__global__ __launch_bounds__(256) void find_thresh(const unsigned* __restrict__ ghist,
                                                   unsigned* __restrict__ thresh) {
  __shared__ unsigned part[256];
  const int t = threadIdx.x;
  unsigned s = 0;
#pragma unroll
  for (int b = 0; b < 16; b++) s += ghist[t * 16 + b];
  part[t] = s;
  __syncthreads();
  if (t == 0) {
    unsigned cum = 0;
    int g = 255;
    for (; g > 0; g--) {
      if (cum + part[g] >= TOPK) break;
      cum += part[g];
    }
    int bsel = g * 16;
    for (int b = g * 16 + 15; b >= g * 16; b--) {
      cum += ghist[b];
      if (cum >= TOPK) { bsel = b; break; }
    }
    *thresh = (unsigned)bsel << 20;
  }
}

// ---------------- collect candidates >= threshold (with margin), recompute EXACT fp32 value ----
__device__ __forceinline__ void cand_push(unsigned kapprox, unsigned thr_m, unsigned idx,
                                          const float* __restrict__ m0f,
                                          const float* __restrict__ m1f,
                                          unsigned long long* __restrict__ cand,
                                          unsigned* __restrict__ counter) {
  if (kapprox >= thr_m) {
    const unsigned row = idx >> 13;   // /8192
    const unsigned col = idx & 8191u; // %8192
    const float4* a4 = (const float4*)(m0f + (size_t)row * H_DIM);
    const float4* b4 = (const float4*)(m1f + (size_t)col * H_DIM);
    float v = 0.f;
#pragma unroll 8
    for (int k = 0; k < H_DIM / 4; k++) {
      float4 a = a4[k], b = b4[k];
      v = fmaf(a.x, b.x, v);
      v = fmaf(a.y, b.y, v);
      v = fmaf(a.z, b.z, v);
      v = fmaf(a.w, b.w, v);
    }
    unsigned p = atomicAdd(counter, 1u);
    if (p < CAND_CAP)
      cand[p] = ((unsigned long long)fkey(v) << 32) |
                (unsigned long long)(0xFFFFFFFFu - idx);
  }
}

__global__ __launch_bounds__(256) void collect(const float* __restrict__ sim,
                                               const unsigned* __restrict__ thresh,
                                               const float* __restrict__ m0f,
                                               const float* __restrict__ m1f,
                                               unsigned long long* __restrict__ cand,
                                               unsigned* __restrict__ counter) {
  const unsigned thr = *thresh;
  // 4096-key margin (~0.03 at sim scale) > 2x observed bf16x3 absmax (0.0156)
  const unsigned thr_m = thr > 4096u ? thr - 4096u : 0u;
  const int stride = gridDim.x * blockDim.x;
  const int total4 = (NCOL * NCOL) / 4;  // 16,777,216
  const float4* s4 = (const float4*)sim;
  for (int i = blockIdx.x * blockDim.x + threadIdx.x; i < total4; i += stride) {
    float4 v = s4[i];
    unsigned base = (unsigned)i * 4u;
    cand_push(fkey(v.x), thr_m, base + 0u, m0f, m1f, cand, counter);
    cand_push(fkey(v.y), thr_m, base + 1u, m0f, m1f, cand, counter);
    cand_push(fkey(v.z), thr_m, base + 2u, m0f, m1f, cand, counter);
    cand_push(fkey(v.w), thr_m, base + 3u, m0f, m1f, cand, counter);
  }
}

// ---------------- top-512: register-resident radix-select (exact 512th key) + 512-sort ----
// Keys are distinct 64-bit (idx in low bits) -> exact kth, no ties. Order matches
// jax.lax.top_k: descending by value, ties impossible; equal values -> smaller idx first
// via the (0xFFFFFFFF - idx) low field.
__global__ __launch_bounds__(1024) void sort_topk(const unsigned long long* __restrict__ cand,
                                                  const unsigned* __restrict__ counter,
                                                  float* __restrict__ out) {
  __shared__ unsigned long long top[TOPK];
  __shared__ unsigned wred[16];
  __shared__ unsigned long long pfx_sh;
  __shared__ unsigned cnt_sh;
  const int t = threadIdx.x;
  const int n = (int)min(*counter, (unsigned)CAND_CAP);
  unsigned long long e[CAND_CAP / 1024];
#pragma unroll
  for (int u = 0; u < CAND_CAP / 1024; ++u) {
    const int i = t + u * 1024;
    e[u] = (i < n) ? cand[i] : 0ULL;
  }
  if (t == 0) cnt_sh = 0;
  __syncthreads();
  // bitwise binary search for the 512th-largest key (max p with #{e >= p} >= 512)
  unsigned long long pfx = 0;
  for (int b = 63; b >= 0; --b) {
    const unsigned long long q = pfx | (1ULL << b);
    unsigned c = 0;
#pragma unroll
    for (int u = 0; u < CAND_CAP / 1024; ++u) c += (e[u] >= q) ? 1u : 0u;
#pragma unroll
    for (int off = 32; off; off >>= 1) c += __shfl_down(c, off, 64);
    if ((t & 63) == 0) wred[t >> 6] = c;
    __syncthreads();
    if (t == 0) {
      unsigned tot = 0;
#pragma unroll
      for (int w = 0; w < 16; ++w) tot += wred[w];
      pfx_sh = (tot >= TOPK) ? q : pfx;
    }
    __syncthreads();
    pfx = pfx_sh;
  }
  // compact: exactly TOPK elements are >= pfx (distinct keys)
#pragma unroll
  for (int u = 0; u < CAND_CAP / 1024; ++u) {
    if (e[u] >= pfx) {
      unsigned p = atomicAdd(&cnt_sh, 1u);
      if (p < TOPK) top[p] = e[u];
    }
  }
  __syncthreads();
  // bitonic sort 512, descending
  for (int k = 2; k <= TOPK; k <<= 1) {
    for (int j = k >> 1; j > 0; j >>= 1) {
      if (t < TOPK) {
        const int l = t ^ j;
        if (l > t) {
          const bool desc = ((t & k) == 0);
          unsigned long long a = top[t], b2 = top[l];
          if (desc ? (a < b2) : (a > b2)) { top[t] = b2; top[l] = a; }
        }
      }
      __syncthreads();
    }
  }
  if (t < TOPK) {
    const unsigned idx = 0xFFFFFFFFu - (unsigned)(top[t] & 0xFFFFFFFFull);
    out[t * 2 + 0] = (float)(idx >> 13);   // row
    out[t * 2 + 1] = (float)(idx & 8191u); // col
  }
}

extern "C" void kernel_launch(void* const* d_in, const int* in_sizes, int n_in,
                              void* d_out, int out_size, void* d_ws, size_t ws_size,
                              hipStream_t stream) {
  const float* desc0 = (const float*)d_in[0];
  const float* desc1 = (const float*)d_in[1];
  const float* W0a = (const float*)d_in[2];
  const float* b0a = (const float*)d_in[3];
  const float* W0b = (const float*)d_in[4];
  const float* b0b = (const float*)d_in[5];
  const float* W1a = (const float*)d_in[6];
  const float* b1a = (const float*)d_in[7];
  const float* W1b = (const float*)d_in[8];
  const float* b1b = (const float*)d_in[9];

  char* ws = (char*)d_ws;
  unsigned* ghist = (unsigned*)ws;                                  // 16KB
  unsigned* counter = (unsigned*)(ws + 16384);                     // 4B
  unsigned* thresh = (unsigned*)(ws + 16388);                      // 4B
  unsigned long long* cand = (unsigned long long*)(ws + 16448);    // 64KB
  float* mdesc0f = (float*)(ws + 131072);                          // 8MB fp32 (exact recompute)
  float* mdesc1f = mdesc0f + 8192 * 256;                           // 8MB
  float* hbuf0 = mdesc1f + 8192 * 256;                             // 8MB
  float* hbuf1 = hbuf0 + 8192 * 256;                               // 8MB
  u16* Ahh = (u16*)(hbuf1 + 8192 * 256);                           // 4MB bf16 hi
  u16* All = Ahh + 8192 * 256;                                     // 4MB bf16 lo
  u16* Bhh = All + 8192 * 256;                                     // 4MB
  u16* Bll = Bhh + 8192 * 256;                                     // 4MB  (total ~48MB)

  float* outf = (float*)d_out;
  float* sim = outf + TOPK * 2;  // sim at float offset 1024 (16B aligned)

  mlp_dual<128, true, false, true><<<1024, 256, 0, stream>>>(
      desc0, W0a, b0a, hbuf0, nullptr, nullptr,
      desc1, W1a, b1a, hbuf1, nullptr, nullptr, ghist, counter);
  mlp_dual<256, false, true, false><<<1024, 256, 0, stream>>>(
      hbuf0, W0b, b0b, mdesc0f, Ahh, All,
      hbuf1, W1b, b1b, mdesc1f, Bhh, Bll, ghist, counter);

  gemm_sim_mfma<<<1024, 512, 0, stream>>>(Ahh, All, Bhh, Bll, sim, ghist);
  find_thresh<<<1, 256, 0, stream>>>(ghist, thresh);
  collect<<<4096, 256, 0, stream>>>(sim, thresh, mdesc0f, mdesc1f, cand, counter);
  sort_topk<<<1, 1024, 0, stream>>>(cand, counter, outf);
}

// Round 5
// 544.947 us; speedup vs baseline: 1.2833x; 1.0430x over previous
//
#include <hip/hip_runtime.h>
#include <stdint.h>

#define H_DIM 256
#define NCOL 8192
#define TOPK 512
#define CAND_CAP 8192

typedef unsigned short u16;
typedef __attribute__((ext_vector_type(8))) __bf16 bf16x8;
typedef __attribute__((ext_vector_type(4))) float f32x4;
typedef unsigned __attribute__((address_space(3))) lds_u32;
typedef const unsigned __attribute__((address_space(1))) glb_u32;

// monotonic float -> uint key (order-preserving for all finite floats)
__device__ __forceinline__ unsigned fkey(float f) {
  unsigned u = __float_as_uint(f);
  unsigned m = (unsigned)((int)u >> 31) | 0x80000000u;
  return u ^ m;
}

__device__ __forceinline__ u16 f2bf_rne(float f) {
  unsigned u = __float_as_uint(f);
  return (u16)((u + 0x7fffu + ((u >> 16) & 1u)) >> 16);
}

__device__ __forceinline__ float bf2f(u16 h) {
  return __uint_as_float(((unsigned)h) << 16);
}

// ---------------- fused 2-layer MLP, both descriptor sets (grid 1024) ------------------
// blocks 0-511: set 0; 512-1023: set 1. block = 16 rows x 256 threads, thread owns 4x4.
// Layer-1 output h lives in LDS (row-wise MLP: row r of layer2 needs only row r of layer1).
// fp32 fmaf chain order (d,d+1,d+2,d+3 sequential over K) is identical to the previous
// bitwise-exact path -> mdesc values unchanged -> collect's exact-recompute guarantee holds.
__global__ __launch_bounds__(256) void mlp_fused(
    const float* __restrict__ X0, const float* __restrict__ W0a,
    const float* __restrict__ b0a, const float* __restrict__ W0b,
    const float* __restrict__ b0b, float* __restrict__ Y0,
    u16* __restrict__ h0, u16* __restrict__ l0,
    const float* __restrict__ X1, const float* __restrict__ W1a,
    const float* __restrict__ b1a, const float* __restrict__ W1b,
    const float* __restrict__ b1b, float* __restrict__ Y1,
    u16* __restrict__ h1, u16* __restrict__ l1,
    unsigned* __restrict__ ghist, unsigned* __restrict__ counter) {
  __shared__ float Xs[16 * 128];  // 8KB
  __shared__ float Hs[16 * 256];  // 16KB
  const int t = threadIdx.x;
  if (blockIdx.x == 0) {  // folded zero_ws (completes before gemm/collect in stream order)
    for (int i = t; i < 4096; i += 256) ghist[i] = 0;
    if (t == 0) *counter = 0;
  }
  const int half = blockIdx.x >> 9;
  const float* X = half ? X1 : X0;
  const float* Wa = half ? W1a : W0a;
  const float* ba = half ? b1a : b0a;
  const float* Wb = half ? W1b : W0b;
  const float* bb_ = half ? b1b : b0b;
  float* Y = half ? Y1 : Y0;
  u16* hi = half ? h1 : h0;
  u16* lo = half ? l1 : l0;
  const int row0 = (blockIdx.x & 511) * 16;

  for (int f = t; f < 512; f += 256) {  // 16*128/4 float4s
    *(float4*)(Xs + f * 4) = *(const float4*)(X + (size_t)row0 * 128 + f * 4);
  }
  __syncthreads();
  const int cg = (t & 63) * 4;  // column base (0..252)
  const int rg = (t >> 6) * 4;  // local row base (0,4,8,12)

  // ---- layer 1: K=128, ReLU, output -> Hs ----
  {
    float acc[4][4];
#pragma unroll
    for (int r = 0; r < 4; r++)
#pragma unroll
      for (int c = 0; c < 4; c++) acc[r][c] = 0.f;
    for (int d = 0; d < 128; d += 4) {
      float4 w0 = *(const float4*)(Wa + (d + 0) * H_DIM + cg);
      float4 w1 = *(const float4*)(Wa + (d + 1) * H_DIM + cg);
      float4 w2 = *(const float4*)(Wa + (d + 2) * H_DIM + cg);
      float4 w3 = *(const float4*)(Wa + (d + 3) * H_DIM + cg);
#pragma unroll
      for (int r = 0; r < 4; r++) {
        float4 x = *(const float4*)(Xs + (rg + r) * 128 + d);  // wave-uniform broadcast
#pragma unroll
        for (int c = 0; c < 4; c++) {
          float a = acc[r][c];
          a = fmaf(x.x, ((const float*)&w0)[c], a);
          a = fmaf(x.y, ((const float*)&w1)[c], a);
          a = fmaf(x.z, ((const float*)&w2)[c], a);
          a = fmaf(x.w, ((const float*)&w3)[c], a);
          acc[r][c] = a;
        }
      }
    }
    const float4 bv = *(const float4*)(ba + cg);
#pragma unroll
    for (int r = 0; r < 4; r++) {
      float4 v;
      v.x = fmaxf(acc[r][0] + bv.x, 0.f);
      v.y = fmaxf(acc[r][1] + bv.y, 0.f);
      v.z = fmaxf(acc[r][2] + bv.z, 0.f);
      v.w = fmaxf(acc[r][3] + bv.w, 0.f);
      *(float4*)(Hs + (rg + r) * 256 + cg) = v;
    }
  }
  __syncthreads();

  // ---- layer 2: K=256 from Hs, emit fp32 + bf16 hi/lo split ----
  {
    float acc[4][4];
#pragma unroll
    for (int r = 0; r < 4; r++)
#pragma unroll
      for (int c = 0; c < 4; c++) acc[r][c] = 0.f;
    for (int d = 0; d < 256; d += 4) {
      float4 w0 = *(const float4*)(Wb + (d + 0) * H_DIM + cg);
      float4 w1 = *(const float4*)(Wb + (d + 1) * H_DIM + cg);
      float4 w2 = *(const float4*)(Wb + (d + 2) * H_DIM + cg);
      float4 w3 = *(const float4*)(Wb + (d + 3) * H_DIM + cg);
#pragma unroll
      for (int r = 0; r < 4; r++) {
        float4 x = *(const float4*)(Hs + (rg + r) * 256 + d);  // wave-uniform broadcast
#pragma unroll
        for (int c = 0; c < 4; c++) {
          float a = acc[r][c];
          a = fmaf(x.x, ((const float*)&w0)[c], a);
          a = fmaf(x.y, ((const float*)&w1)[c], a);
          a = fmaf(x.z, ((const float*)&w2)[c], a);
          a = fmaf(x.w, ((const float*)&w3)[c], a);
          acc[r][c] = a;
        }
      }
    }
    const float4 bv = *(const float4*)(bb_ + cg);
#pragma unroll
    for (int r = 0; r < 4; r++) {
      float4 v;
      v.x = acc[r][0] + bv.x;
      v.y = acc[r][1] + bv.y;
      v.z = acc[r][2] + bv.z;
      v.w = acc[r][3] + bv.w;
      const size_t grow = (size_t)(row0 + rg + r);
      *(float4*)(Y + grow * H_DIM + cg) = v;
      ushort4 hv, lv;
      hv.x = f2bf_rne(v.x); lv.x = f2bf_rne(v.x - bf2f(hv.x));
      hv.y = f2bf_rne(v.y); lv.y = f2bf_rne(v.y - bf2f(hv.y));
      hv.z = f2bf_rne(v.z); lv.z = f2bf_rne(v.z - bf2f(hv.z));
      hv.w = f2bf_rne(v.w); lv.w = f2bf_rne(v.w - bf2f(hv.w));
      *(ushort4*)(hi + grow * H_DIM + cg) = hv;
      *(ushort4*)(lo + grow * H_DIM + cg) = lv;
    }
  }
}

// ---------------- big GEMM (bf16x3), phase-split counted-vmcnt ----------------------------
// 256x256 tile, 512 threads (8 waves, 2M x 4N), per-wave 128x64 output, K-chunks of 32.
// LDS row = 128B [Xh(32 bf16) | Xl(32 bf16)], XOR-swizzle byte ^= ((row&7)<<4) applied via
// inverse-swizzled per-lane global source (linear global_load_lds dest) + swizzled ds_read.
// Chunk skeleton (proven r3/r4): STAGE(next) -> vmcnt(8) -> barrier -> compute -> barrier.
// NEW: chunk compute split into 3 barrier-delimited phases (32 MFMA each) with just-in-time
// fragment reads -> wave role diversity so setprio pays (T3/T5, m218b); barriers are
// scheduling-only (all intra-chunk reads hit the same buffer -> no correctness hazard).
__global__ __launch_bounds__(512, 2) void gemm_sim_mfma(const u16* __restrict__ Ah,
                                                        const u16* __restrict__ Al,
                                                        const u16* __restrict__ Bh,
                                                        const u16* __restrict__ Bl,
                                                        float* __restrict__ C,
                                                        unsigned* __restrict__ ghist) {
  __shared__ __align__(16) char SB[131072];  // 2 bufs x (A2 32KB + B2 32KB)
  const int t = threadIdx.x;
  const int wave = t >> 6, lane = t & 63;
  const int wm = wave >> 2, wn = wave & 3;  // 2M x 4N waves
  // XCD swizzle: 1024 blocks, 1024%8==0 -> bijective
  const int bid = blockIdx.x;
  const int swz = (bid & 7) * 128 + (bid >> 3);
  const int m0 = (swz >> 5) * 256, n0 = (swz & 31) * 256;

  f32x4 acc[8][4];
#pragma unroll
  for (int i = 0; i < 8; i++)
#pragma unroll
    for (int j = 0; j < 4; j++) acc[i][j] = (f32x4){0.f, 0.f, 0.f, 0.f};

  // staging: round i covers LDS bytes [i*8192,+8192): row = i*64 + (t>>3), slot = t&7.
  // source slot = slot ^ (row&7) (involution); slots 0-3 -> Xh, 4-7 -> Xl.
  const int srow8 = t >> 3;
  const int sA = (t & 7) ^ (srow8 & 7);
  const u16* pAsrc = (sA < 4) ? Ah : Al;
  const u16* pBsrc = (sA < 4) ? Bh : Bl;
  const int scolE = (sA & 3) * 8;  // elems within the 32-elem k-chunk
  // fragment read: row lrow in 16-row group, k-group byte kq16; swizzle key = lrow&7
  const int lrow = lane & 15;
  const int kq16 = (lane >> 4) << 4;
  const int asz = (lrow & 7) << 4;
  const int cH = kq16 ^ asz;         // hi operand col byte within 128B row
  const int cL = (64 + kq16) ^ asz;  // lo operand col byte

  auto STAGE = [&](int bsel, int tt) {
    const int kofs = tt * 32;
    char* base = SB + bsel * 65536;
    const size_t ar = (size_t)(m0 + srow8) * H_DIM + kofs + scolE;
    const size_t br = (size_t)(n0 + srow8) * H_DIM + kofs + scolE;
#pragma unroll
    for (int i = 0; i < 4; i++)
      __builtin_amdgcn_global_load_lds((glb_u32*)(pAsrc + ar + (size_t)i * 64 * H_DIM),
                                       (lds_u32*)(base + i * 8192 + wave * 1024), 16, 0, 0);
#pragma unroll
    for (int i = 0; i < 4; i++)
      __builtin_amdgcn_global_load_lds((glb_u32*)(pBsrc + br + (size_t)i * 64 * H_DIM),
                                       (lds_u32*)(base + 32768 + i * 8192 + wave * 1024), 16, 0, 0);
  };

  STAGE(0, 0);
  for (int tt = 0; tt < 8; ++tt) {
    if (tt < 7) {
      STAGE((tt + 1) & 1, tt + 1);
      asm volatile("s_waitcnt vmcnt(8)" ::: "memory");  // chunk tt staged; tt+1 in flight
    } else {
      asm volatile("s_waitcnt vmcnt(0)" ::: "memory");
    }
    __builtin_amdgcn_s_barrier();  // buf[tt&1] ready, all waves aligned
    asm volatile("" ::: "memory");
    const char* bb = SB + (tt & 1) * 65536;
    const char* bA = bb + (wm * 128 + lrow) * 128;
    const char* bB = bb + 32768 + (wn * 64 + lrow) * 128;

    // phase 1: read aH,bH; MFMA aH x bH
    bf16x8 aH[8], bH[4];
#pragma unroll
    for (int fm = 0; fm < 8; fm++) aH[fm] = *(const bf16x8*)(bA + fm * 2048 + cH);
#pragma unroll
    for (int fn = 0; fn < 4; fn++) bH[fn] = *(const bf16x8*)(bB + fn * 2048 + cH);
    __builtin_amdgcn_s_setprio(1);
#pragma unroll
    for (int fm = 0; fm < 8; fm++)
#pragma unroll
      for (int fn = 0; fn < 4; fn++)
        acc[fm][fn] = __builtin_amdgcn_mfma_f32_16x16x32_bf16(aH[fm], bH[fn], acc[fm][fn], 0, 0, 0);
    __builtin_amdgcn_s_setprio(0);
    __builtin_amdgcn_s_barrier();  // scheduling barrier (no buffer hazard within chunk)

    // phase 2: read bL; MFMA aH x bL
    {
      bf16x8 bL[4];
#pragma unroll
      for (int fn = 0; fn < 4; fn++) bL[fn] = *(const bf16x8*)(bB + fn * 2048 + cL);
      __builtin_amdgcn_s_setprio(1);
#pragma unroll
      for (int fm = 0; fm < 8; fm++)
#pragma unroll
        for (int fn = 0; fn < 4; fn++)
          acc[fm][fn] = __builtin_amdgcn_mfma_f32_16x16x32_bf16(aH[fm], bL[fn], acc[fm][fn], 0, 0, 0);
      __builtin_amdgcn_s_setprio(0);
    }
    __builtin_amdgcn_s_barrier();

    // phase 3: read aL; MFMA aL x bH
    {
      bf16x8 aL[8];
#pragma unroll
      for (int fm = 0; fm < 8; fm++) aL[fm] = *(const bf16x8*)(bA + fm * 2048 + cL);
      __builtin_amdgcn_s_setprio(1);
#pragma unroll
      for (int fm = 0; fm < 8; fm++)
#pragma unroll
        for (int fn = 0; fn < 4; fn++)
          acc[fm][fn] = __builtin_amdgcn_mfma_f32_16x16x32_bf16(aL[fm], bH[fn], acc[fm][fn], 0, 0, 0);
      __builtin_amdgcn_s_setprio(0);
    }
    __builtin_amdgcn_s_barrier();  // chunk end: all waves done reading buf[tt&1]
    asm volatile("" ::: "memory");
  }

  // ---------- epilogue: LDS-staged coalesced C-store + histogram ----------
  // C/D frag layout: col=lane&15, row=(lane>>4)*4+q (m89-verified).
  unsigned* hist = (unsigned*)SB;    // 16KB
  float* Ct = (float*)(SB + 16384);  // [64][260] fp32, pad 4
  for (int i = t; i < 4096; i += 512) hist[i] = 0;
  __syncthreads();
#pragma unroll
  for (int ch = 0; ch < 4; ++ch) {  // 64-row chunks of the 256-row tile
    if (wm == (ch >> 1)) {
      const int fmb = (ch & 1) * 4;
#pragma unroll
      for (int fi = 0; fi < 4; fi++)
#pragma unroll
        for (int fn = 0; fn < 4; fn++)
#pragma unroll
          for (int q = 0; q < 4; q++)
            Ct[(fi * 16 + (lane >> 4) * 4 + q) * 260 + wn * 64 + fn * 16 + lrow] =
                acc[fmb + fi][fn][q];
    }
    __syncthreads();
#pragma unroll
    for (int u = 0; u < 8; ++u) {
      const int idx = t + u * 512;  // 4096 float4 = 64x256 floats
      const int row = idx >> 6, c4 = idx & 63;
      float4 v = *(const float4*)(Ct + row * 260 + c4 * 4);
      *(float4*)(C + (size_t)(m0 + ch * 64 + row) * NCOL + n0 + c4 * 4) = v;
      atomicAdd(&hist[fkey(v.x) >> 20], 1u);
      atomicAdd(&hist[fkey(v.y) >> 20], 1u);
      atomicAdd(&hist[fkey(v.z) >> 20], 1u);
      atomicAdd(&hist[fkey(v.w) >> 20], 1u);
    }
    __syncthreads();
  }
  for (int bq = t; bq < 4096; bq += 512) {
    unsigned cc = hist[bq];
    if (cc) atomicAdd(&ghist[bq], cc);
  }
}

// ---------------- collect: inline threshold (parallel suffix scan) + candidate recompute ----
// ghist is complete & visible at the kernel boundary (implicit release at gemm end).
// Each block recomputes the threshold (<1us, parallel): smallest bin b* with
// count(key >= b*<<20) >= TOPK — identical semantics to the old find_thresh.
__device__ __forceinline__ void cand_push(unsigned kapprox, unsigned thr_m, unsigned idx,
                                          const float* __restrict__ m0f,
                                          const float* __restrict__ m1f,
                                          unsigned long long* __restrict__ cand,
                                          unsigned* __restrict__ counter) {
  if (kapprox >= thr_m) {
    const unsigned row = idx >> 13;   // /8192
    const unsigned col = idx & 8191u; // %8192
    const float4* a4 = (const float4*)(m0f + (size_t)row * H_DIM);
    const float4* b4 = (const float4*)(m1f + (size_t)col * H_DIM);
    float v = 0.f;
#pragma unroll 8
    for (int k = 0; k < H_DIM / 4; k++) {
      float4 a = a4[k], b = b4[k];
      v = fmaf(a.x, b.x, v);
      v = fmaf(a.y, b.y, v);
      v = fmaf(a.z, b.z, v);
      v = fmaf(a.w, b.w, v);
    }
    unsigned p = atomicAdd(counter, 1u);
    if (p < CAND_CAP)
      cand[p] = ((unsigned long long)fkey(v) << 32) |
                (unsigned long long)(0xFFFFFFFFu - idx);
  }
}

__global__ __launch_bounds__(256) void collect(const float* __restrict__ sim,
                                               const unsigned* __restrict__ ghist,
                                               const float* __restrict__ m0f,
                                               const float* __restrict__ m1f,
                                               unsigned long long* __restrict__ cand,
                                               unsigned* __restrict__ counter) {
  __shared__ unsigned part[256];
  __shared__ unsigned thr_sh;
  const int t = threadIdx.x;
  {
    unsigned s = 0;
#pragma unroll
    for (int b = 0; b < 16; b++) s += ghist[t * 16 + b];
    part[t] = s;
    __syncthreads();
    // suffix sums over groups: part[t] := sum_{g>=t} part[g]
    for (int off = 1; off < 256; off <<= 1) {
      unsigned v = part[t] + ((t + off < 256) ? part[t + off] : 0u);
      __syncthreads();
      part[t] = v;
      __syncthreads();
    }
    // unique boundary: suffix[t] >= TOPK and suffix[t+1] < TOPK
    if (part[t] >= TOPK && (t == 255 || part[t + 1] < TOPK)) {
      unsigned cum = (t == 255) ? 0u : part[t + 1];
      int bsel = t * 16;
      for (int b = t * 16 + 15; b >= t * 16; --b) {
        cum += ghist[b];
        if (cum >= TOPK) { bsel = b; break; }
      }
      thr_sh = (unsigned)bsel << 20;
    }
    __syncthreads();
  }
  const unsigned thr = thr_sh;
  // 4096-key margin (~0.03 at sim scale) > 2x observed bf16x3 absmax (0.0156)
  const unsigned thr_m = thr > 4096u ? thr - 4096u : 0u;
  const int stride = gridDim.x * blockDim.x;
  const int total4 = (NCOL * NCOL) / 4;  // 16,777,216
  const float4* s4 = (const float4*)sim;
  for (int i = blockIdx.x * blockDim.x + threadIdx.x; i < total4; i += stride) {
    float4 v = s4[i];
    unsigned base = (unsigned)i * 4u;
    cand_push(fkey(v.x), thr_m, base + 0u, m0f, m1f, cand, counter);
    cand_push(fkey(v.y), thr_m, base + 1u, m0f, m1f, cand, counter);
    cand_push(fkey(v.z), thr_m, base + 2u, m0f, m1f, cand, counter);
    cand_push(fkey(v.w), thr_m, base + 3u, m0f, m1f, cand, counter);
  }
}

// ---------------- top-512: register-resident radix-select (exact 512th key) + 512-sort ----
// Keys are distinct 64-bit (idx in low bits) -> exact kth, no ties. Order matches
// jax.lax.top_k: descending by value; equal values -> smaller idx first via the
// (0xFFFFFFFF - idx) low field.
__global__ __launch_bounds__(1024) void sort_topk(const unsigned long long* __restrict__ cand,
                                                  const unsigned* __restrict__ counter,
                                                  float* __restrict__ out) {
  __shared__ unsigned long long top[TOPK];
  __shared__ unsigned wred[16];
  __shared__ unsigned long long pfx_sh;
  __shared__ unsigned cnt_sh;
  const int t = threadIdx.x;
  const int n = (int)min(*counter, (unsigned)CAND_CAP);
  unsigned long long e[CAND_CAP / 1024];
#pragma unroll
  for (int u = 0; u < CAND_CAP / 1024; ++u) {
    const int i = t + u * 1024;
    e[u] = (i < n) ? cand[i] : 0ULL;
  }
  if (t == 0) cnt_sh = 0;
  __syncthreads();
  // bitwise binary search for the 512th-largest key (max p with #{e >= p} >= 512)
  unsigned long long pfx = 0;
  for (int b = 63; b >= 0; --b) {
    const unsigned long long q = pfx | (1ULL << b);
    unsigned c = 0;
#pragma unroll
    for (int u = 0; u < CAND_CAP / 1024; ++u) c += (e[u] >= q) ? 1u : 0u;
#pragma unroll
    for (int off = 32; off; off >>= 1) c += __shfl_down(c, off, 64);
    if ((t & 63) == 0) wred[t >> 6] = c;
    __syncthreads();
    if (t == 0) {
      unsigned tot = 0;
#pragma unroll
      for (int w = 0; w < 16; ++w) tot += wred[w];
      pfx_sh = (tot >= TOPK) ? q : pfx;
    }
    __syncthreads();
    pfx = pfx_sh;
  }
  // compact: exactly TOPK elements are >= pfx (distinct keys)
#pragma unroll
  for (int u = 0; u < CAND_CAP / 1024; ++u) {
    if (e[u] >= pfx) {
      unsigned p = atomicAdd(&cnt_sh, 1u);
      if (p < TOPK) top[p] = e[u];
    }
  }
  __syncthreads();
  // bitonic sort 512, descending
  for (int k = 2; k <= TOPK; k <<= 1) {
    for (int j = k >> 1; j > 0; j >>= 1) {
      if (t < TOPK) {
        const int l = t ^ j;
        if (l > t) {
          const bool desc = ((t & k) == 0);
          unsigned long long a = top[t], b2 = top[l];
          if (desc ? (a < b2) : (a > b2)) { top[t] = b2; top[l] = a; }
        }
      }
      __syncthreads();
    }
  }
  if (t < TOPK) {
    const unsigned idx = 0xFFFFFFFFu - (unsigned)(top[t] & 0xFFFFFFFFull);
    out[t * 2 + 0] = (float)(idx >> 13);   // row
    out[t * 2 + 1] = (float)(idx & 8191u); // col
  }
}

extern "C" void kernel_launch(void* const* d_in, const int* in_sizes, int n_in,
                              void* d_out, int out_size, void* d_ws, size_t ws_size,
                              hipStream_t stream) {
  const float* desc0 = (const float*)d_in[0];
  const float* desc1 = (const float*)d_in[1];
  const float* W0a = (const float*)d_in[2];
  const float* b0a = (const float*)d_in[3];
  const float* W0b = (const float*)d_in[4];
  const float* b0b = (const float*)d_in[5];
  const float* W1a = (const float*)d_in[6];
  const float* b1a = (const float*)d_in[7];
  const float* W1b = (const float*)d_in[8];
  const float* b1b = (const float*)d_in[9];

  char* ws = (char*)d_ws;
  unsigned* ghist = (unsigned*)ws;                                  // 16KB
  unsigned* counter = (unsigned*)(ws + 16384);                     // 4B
  unsigned long long* cand = (unsigned long long*)(ws + 16448);    // 64KB
  float* mdesc0f = (float*)(ws + 131072);                          // 8MB fp32 (exact recompute)
  float* mdesc1f = mdesc0f + 8192 * 256;                           // 8MB
  u16* Ahh = (u16*)(mdesc1f + 8192 * 256);                         // 4MB bf16 hi
  u16* All = Ahh + 8192 * 256;                                     // 4MB bf16 lo
  u16* Bhh = All + 8192 * 256;                                     // 4MB
  u16* Bll = Bhh + 8192 * 256;                                     // 4MB  (total ~32MB)

  float* outf = (float*)d_out;
  float* sim = outf + TOPK * 2;  // sim at float offset 1024 (16B aligned)

  mlp_fused<<<1024, 256, 0, stream>>>(
      desc0, W0a, b0a, W0b, b0b, mdesc0f, Ahh, All,
      desc1, W1a, b1a, W1b, b1b, mdesc1f, Bhh, Bll, ghist, counter);

  gemm_sim_mfma<<<1024, 512, 0, stream>>>(Ahh, All, Bhh, Bll, sim, ghist);
  collect<<<4096, 256, 0, stream>>>(sim, ghist, mdesc0f, mdesc1f, cand, counter);
  sort_topk<<<1, 1024, 0, stream>>>(cand, counter, outf);
}